// Round 1
// baseline (372841.455 us; speedup 1.0000x reference)
//
#include <hip/hip_runtime.h>
#include <math.h>

// Problem constants (match reference): B=128, T=512, IN=64, H=1024, OUT=1
#define Hdim 1024
#define Bdim 128
#define Tdim 512
#define INdim 64

__device__ __forceinline__ float sigmoidf_(float x) { return 1.0f / (1.0f + expf(-x)); }

// ---------------------------------------------------------------------------
// init: zero states, precompute boundary gate biases bi0/bi1 [B,H]
// grid 256 x 512 threads -> 131072 = B*H
// ---------------------------------------------------------------------------
__global__ __launch_bounds__(512) void init_kernel(
    const float* __restrict__ bnd,  // [B,2]
    const float* __restrict__ Wb0,  // [H,2]
    const float* __restrict__ bb0,  // [H]
    const float* __restrict__ Wb1,  // [H,2]
    const float* __restrict__ bb1,  // [H]
    float* __restrict__ h0a, float* __restrict__ h1a,
    float* __restrict__ c0, float* __restrict__ c1,
    float* __restrict__ bi0, float* __restrict__ bi1)
{
    int idx = blockIdx.x * 512 + threadIdx.x;   // b*H + h
    int b = idx >> 10;
    int h = idx & 1023;
    float b0v = bnd[b * 2 + 0];
    float b1v = bnd[b * 2 + 1];
    bi0[idx] = b0v * Wb0[h * 2 + 0] + b1v * Wb0[h * 2 + 1] + bb0[h];
    bi1[idx] = b0v * Wb1[h * 2 + 0] + b1v * Wb1[h * 2 + 1] + bb1[h];
    h0a[idx] = 0.0f;
    h1a[idx] = 0.0f;
    c0[idx] = 0.0f;
    c1[idx] = 0.0f;
}

// ---------------------------------------------------------------------------
// phase1 (layer 0, one timestep): g0 = x_t@Wx0^T + h0@Uh0^T + bx0 + bh0,
// then LSTM cell with bi0 on forget gate. Fused: each thread owns one (b,h)
// cell = 4 gate rows. Tile: full 128 batch x 4 h-cols per block -> F=1 weight
// reuse (each weight row read by exactly one block). grid 256 x 512 threads.
// ---------------------------------------------------------------------------
__global__ __launch_bounds__(512) void phase1_kernel(
    const float* __restrict__ x,    // [B,T,IN]
    int t,
    const float* __restrict__ Wx0,  // [4H,IN]
    const float* __restrict__ bx0,  // [4H]
    const float* __restrict__ Uh0,  // [4H,H]
    const float* __restrict__ bh0,  // [4H]
    const float* __restrict__ h0r,  // read h0(t-1) [B,H]
    float* __restrict__ h0w,        // write h0(t)  [B,H]
    float* __restrict__ c0,         // in/out [B,H]
    const float* __restrict__ bi0)  // [B,H]
{
    int tid = threadIdx.x;
    int h = blockIdx.x * 4 + (tid & 3);
    int b = tid >> 2;  // 0..127

    const float4* wi = (const float4*)(Uh0 + (size_t)h * Hdim);
    const float4* wf = (const float4*)(Uh0 + (size_t)(Hdim + h) * Hdim);
    const float4* wo = (const float4*)(Uh0 + (size_t)(2 * Hdim + h) * Hdim);
    const float4* wg = (const float4*)(Uh0 + (size_t)(3 * Hdim + h) * Hdim);
    const float4* hv = (const float4*)(h0r + (size_t)b * Hdim);

    int cidx = b * Hdim + h;
    float ai = bx0[h] + bh0[h];
    float af = bx0[Hdim + h] + bh0[Hdim + h] + bi0[cidx];
    float ao = bx0[2 * Hdim + h] + bh0[2 * Hdim + h];
    float ag = bx0[3 * Hdim + h] + bh0[3 * Hdim + h];

    #pragma unroll 4
    for (int k = 0; k < Hdim / 4; ++k) {
        float4 hh = hv[k];
        float4 a = wi[k];
        ai += a.x * hh.x + a.y * hh.y + a.z * hh.z + a.w * hh.w;
        float4 f = wf[k];
        af += f.x * hh.x + f.y * hh.y + f.z * hh.z + f.w * hh.w;
        float4 o = wo[k];
        ao += o.x * hh.x + o.y * hh.y + o.z * hh.z + o.w * hh.w;
        float4 g = wg[k];
        ag += g.x * hh.x + g.y * hh.y + g.z * hh.z + g.w * hh.w;
    }

    // x projection (K = 64)
    const float4* xi = (const float4*)(Wx0 + (size_t)h * INdim);
    const float4* xf = (const float4*)(Wx0 + (size_t)(Hdim + h) * INdim);
    const float4* xo = (const float4*)(Wx0 + (size_t)(2 * Hdim + h) * INdim);
    const float4* xg = (const float4*)(Wx0 + (size_t)(3 * Hdim + h) * INdim);
    const float4* xv = (const float4*)(x + ((size_t)b * Tdim + t) * INdim);
    #pragma unroll
    for (int k = 0; k < INdim / 4; ++k) {
        float4 hh = xv[k];
        float4 a = xi[k];
        ai += a.x * hh.x + a.y * hh.y + a.z * hh.z + a.w * hh.w;
        float4 f = xf[k];
        af += f.x * hh.x + f.y * hh.y + f.z * hh.z + f.w * hh.w;
        float4 o = xo[k];
        ao += o.x * hh.x + o.y * hh.y + o.z * hh.z + o.w * hh.w;
        float4 g = xg[k];
        ag += g.x * hh.x + g.y * hh.y + g.z * hh.z + g.w * hh.w;
    }

    float I = sigmoidf_(ai);
    float F = sigmoidf_(af);
    float O = sigmoidf_(ao);
    float G = tanhf(ag);
    float c = F * c0[cidx] + I * G;
    c0[cidx] = c;
    h0w[cidx] = O * tanhf(c);
}

// ---------------------------------------------------------------------------
// phase2 (layer 1, one timestep): g1 = h0n@Wx1^T + h1@Uh1^T + bx1 + bh1,
// then LSTM cell with bi1. Same tiling as phase1. grid 256 x 512 threads.
// ---------------------------------------------------------------------------
__global__ __launch_bounds__(512) void phase2_kernel(
    const float* __restrict__ Wx1,  // [4H,H]
    const float* __restrict__ bx1,  // [4H]
    const float* __restrict__ Uh1,  // [4H,H]
    const float* __restrict__ bh1,  // [4H]
    const float* __restrict__ h0n,  // h0(t) from phase1 [B,H]
    const float* __restrict__ h1r,  // h1(t-1) [B,H]
    float* __restrict__ h1w,        // h1(t) [B,H]
    float* __restrict__ c1,         // in/out [B,H]
    const float* __restrict__ bi1)  // [B,H]
{
    int tid = threadIdx.x;
    int h = blockIdx.x * 4 + (tid & 3);
    int b = tid >> 2;

    const float4* wi = (const float4*)(Wx1 + (size_t)h * Hdim);
    const float4* wf = (const float4*)(Wx1 + (size_t)(Hdim + h) * Hdim);
    const float4* wo = (const float4*)(Wx1 + (size_t)(2 * Hdim + h) * Hdim);
    const float4* wg = (const float4*)(Wx1 + (size_t)(3 * Hdim + h) * Hdim);
    const float4* ui = (const float4*)(Uh1 + (size_t)h * Hdim);
    const float4* uf = (const float4*)(Uh1 + (size_t)(Hdim + h) * Hdim);
    const float4* uo = (const float4*)(Uh1 + (size_t)(2 * Hdim + h) * Hdim);
    const float4* ug = (const float4*)(Uh1 + (size_t)(3 * Hdim + h) * Hdim);
    const float4* hx = (const float4*)(h0n + (size_t)b * Hdim);
    const float4* hh1 = (const float4*)(h1r + (size_t)b * Hdim);

    int cidx = b * Hdim + h;
    float ai = bx1[h] + bh1[h];
    float af = bx1[Hdim + h] + bh1[Hdim + h] + bi1[cidx];
    float ao = bx1[2 * Hdim + h] + bh1[2 * Hdim + h];
    float ag = bx1[3 * Hdim + h] + bh1[3 * Hdim + h];

    #pragma unroll 4
    for (int k = 0; k < Hdim / 4; ++k) {
        float4 hh = hx[k];
        float4 a = wi[k];
        ai += a.x * hh.x + a.y * hh.y + a.z * hh.z + a.w * hh.w;
        float4 f = wf[k];
        af += f.x * hh.x + f.y * hh.y + f.z * hh.z + f.w * hh.w;
        float4 o = wo[k];
        ao += o.x * hh.x + o.y * hh.y + o.z * hh.z + o.w * hh.w;
        float4 g = wg[k];
        ag += g.x * hh.x + g.y * hh.y + g.z * hh.z + g.w * hh.w;
    }
    #pragma unroll 4
    for (int k = 0; k < Hdim / 4; ++k) {
        float4 hh = hh1[k];
        float4 a = ui[k];
        ai += a.x * hh.x + a.y * hh.y + a.z * hh.z + a.w * hh.w;
        float4 f = uf[k];
        af += f.x * hh.x + f.y * hh.y + f.z * hh.z + f.w * hh.w;
        float4 o = uo[k];
        ao += o.x * hh.x + o.y * hh.y + o.z * hh.z + o.w * hh.w;
        float4 g = ug[k];
        ag += g.x * hh.x + g.y * hh.y + g.z * hh.z + g.w * hh.w;
    }

    float I = sigmoidf_(ai);
    float F = sigmoidf_(af);
    float O = sigmoidf_(ao);
    float G = tanhf(ag);
    float c = F * c1[cidx] + I * G;
    c1[cidx] = c;
    h1w[cidx] = O * tanhf(c);
}

// ---------------------------------------------------------------------------
// final head: out[b] = dot(h1_last[b,:], fcW) + fcb. grid 128 x 256 threads.
// ---------------------------------------------------------------------------
__global__ __launch_bounds__(256) void fc_kernel(
    const float* __restrict__ h1,   // [B,H]
    const float* __restrict__ fcW,  // [1,H]
    const float* __restrict__ fcb,  // [1]
    float* __restrict__ out)        // [B,1]
{
    int b = blockIdx.x;
    int tid = threadIdx.x;
    float s = 0.0f;
    for (int j = tid; j < Hdim; j += 256) s += h1[(size_t)b * Hdim + j] * fcW[j];
    #pragma unroll
    for (int off = 32; off > 0; off >>= 1) s += __shfl_down(s, off, 64);
    __shared__ float ls[4];
    if ((tid & 63) == 0) ls[tid >> 6] = s;
    __syncthreads();
    if (tid == 0) out[b] = ls[0] + ls[1] + ls[2] + ls[3] + fcb[0];
}

// ---------------------------------------------------------------------------
extern "C" void kernel_launch(void* const* d_in, const int* in_sizes, int n_in,
                              void* d_out, int out_size, void* d_ws, size_t ws_size,
                              hipStream_t stream) {
    const float* x        = (const float*)d_in[0];
    const float* boundary = (const float*)d_in[1];
    const float* Wx0      = (const float*)d_in[2];
    const float* bx0      = (const float*)d_in[3];
    const float* Uh0      = (const float*)d_in[4];
    const float* bh0      = (const float*)d_in[5];
    const float* Wb0      = (const float*)d_in[6];
    const float* bb0      = (const float*)d_in[7];
    const float* Wx1      = (const float*)d_in[8];
    const float* bx1      = (const float*)d_in[9];
    const float* Uh1      = (const float*)d_in[10];
    const float* bh1      = (const float*)d_in[11];
    const float* Wb1      = (const float*)d_in[12];
    const float* bb1      = (const float*)d_in[13];
    const float* fcW      = (const float*)d_in[14];
    const float* fcb      = (const float*)d_in[15];
    float* out = (float*)d_out;

    // workspace layout (floats): 8 buffers of B*H = 131072 -> 4 MB total
    float* ws  = (float*)d_ws;
    const size_t S = (size_t)Bdim * Hdim;
    float* h0a = ws + 0 * S;
    float* h0b = ws + 1 * S;
    float* h1a = ws + 2 * S;
    float* h1b = ws + 3 * S;
    float* c0  = ws + 4 * S;
    float* c1  = ws + 5 * S;
    float* bi0 = ws + 6 * S;
    float* bi1 = ws + 7 * S;

    init_kernel<<<256, 512, 0, stream>>>(boundary, Wb0, bb0, Wb1, bb1,
                                         h0a, h1a, c0, c1, bi0, bi1);

    for (int t = 0; t < Tdim; ++t) {
        int par = t & 1;
        const float* h0r = par ? h0b : h0a;
        float*       h0w = par ? h0a : h0b;
        const float* h1r = par ? h1b : h1a;
        float*       h1w = par ? h1a : h1b;
        phase1_kernel<<<Hdim / 4, 512, 0, stream>>>(x, t, Wx0, bx0, Uh0, bh0,
                                                    h0r, h0w, c0, bi0);
        phase2_kernel<<<Hdim / 4, 512, 0, stream>>>(Wx1, bx1, Uh1, bh1,
                                                    h0w, h1r, h1w, c1, bi1);
    }
    // t = T-1 has par = 1 -> final h1 written to h1a
    fc_kernel<<<Bdim, 256, 0, stream>>>(h1a, fcW, fcb, out);
}

// Round 2
// 19744.008 us; speedup vs baseline: 18.8838x; 18.8838x over previous
//
#include <hip/hip_runtime.h>
#include <math.h>

// ---------------------------------------------------------------------------
// Persistent-RNN LSTM for MI355X.
//   B=128, T=512, IN=64, H=1024, 2 layers, head OUT=1 on last step.
// Design:
//  - 256 WGs x 512 threads (8 waves), cooperative launch, 1 WG/CU.
//  - Weights f16-resident: layer0 [Uh0|Wx0] slice (16 rows x 1088) in LDS
//    (35 KB); layer1 [Wx1/Uh1] slice in VGPRs (32 half8 frags/lane = 128 VGPR).
//  - WG owns 4 h-columns => 16 gate rows (order i0..3,f0..3,o0..3,g0..3).
//  - mfma_f32_16x16x32_f16: A = h-state frags from global (f16), B = weights.
//  - Software pipeline: iter s computes layer1(s) AND layer0(s+1), sharing
//    h0(s) fragment loads. 513 grid barriers total.
//  - Layer1 K=2048 split: waves 0-3 k<1024 (A=h0), waves 4-7 k>=1024 (A=h1);
//    partials exchanged via LDS. Waves 0-3 also compute BOTH layer0 tiles
//    (fused with their h0 loads); acc for tile 2p+1 handed to wave 4+p.
//  - Cell math fp32; c-state in registers; gate gather via shfl_xor(4,8,12).
//  - Grid barrier: monotonic atomic counter + __threadfence (wbl2/inv gives
//    cross-XCD visibility of f16 h-stores).
// ---------------------------------------------------------------------------

#define Hd 1024
#define Bd 128
#define Td 512
#define INd 64
#define NWG 256
#define NTHR 512

typedef _Float16 f16;
typedef _Float16 half8 __attribute__((ext_vector_type(8)));
typedef float f32x4 __attribute__((ext_vector_type(4)));

// ---------------- init: bi0/bi1, zero h buffers, zero barrier ----------------
__global__ __launch_bounds__(512) void init_state(
    const float* __restrict__ bnd, const float* __restrict__ Wb0,
    const float* __restrict__ bb0, const float* __restrict__ Wb1,
    const float* __restrict__ bb1,
    float* __restrict__ bi0, float* __restrict__ bi1,
    f16* __restrict__ h0buf, f16* __restrict__ h1buf,
    unsigned int* __restrict__ cnt)
{
    int idx = blockIdx.x * 512 + threadIdx.x;   // [0, B*H)
    int b = idx >> 10;
    int h = idx & 1023;
    float b0v = bnd[b * 2 + 0], b1v = bnd[b * 2 + 1];
    bi0[idx] = b0v * Wb0[h * 2 + 0] + b1v * Wb0[h * 2 + 1] + bb0[h];
    bi1[idx] = b0v * Wb1[h * 2 + 0] + b1v * Wb1[h * 2 + 1] + bb1[h];
    h0buf[idx] = (f16)0.f;  h0buf[idx + Bd * Hd] = (f16)0.f;
    h1buf[idx] = (f16)0.f;  h1buf[idx + Bd * Hd] = (f16)0.f;
    if (idx == 0) *cnt = 0u;
}

// ---------------- transpose x [B,T,IN] f32 -> xT [T,B,IN] f16 ----------------
__global__ __launch_bounds__(512) void xpose(
    const float* __restrict__ x, f16* __restrict__ xT)
{
    int idx = blockIdx.x * 512 + threadIdx.x;   // [0, B*T*IN)
    int b = idx >> 15;           // T*IN = 32768
    int t = (idx >> 6) & 511;
    int i = idx & 63;
    xT[((size_t)t * Bd + b) * INd + i] = (f16)x[idx];
}

// ---------------- persistent LSTM ----------------
__global__ __launch_bounds__(NTHR, 2) void lstm_persist(
    const f16* __restrict__ xT,
    f16* __restrict__ h0buf, f16* __restrict__ h1buf,
    const float* __restrict__ bi0, const float* __restrict__ bi1,
    const float* __restrict__ Wx0, const float* __restrict__ bx0,
    const float* __restrict__ Uh0, const float* __restrict__ bh0,
    const float* __restrict__ Wx1, const float* __restrict__ bx1,
    const float* __restrict__ Uh1, const float* __restrict__ bh1,
    const float* __restrict__ fcW, const float* __restrict__ fcb,
    float* __restrict__ out, unsigned int* __restrict__ cnt)
{
    const int tid  = threadIdx.x;
    const int w    = tid >> 6;        // wave 0..7
    const int lane = tid & 63;
    const int n    = lane & 15;       // frag col (gate-col within WG)
    const int q    = lane >> 4;       // 0..3
    const int wg   = blockIdx.x;
    const int c0wg = wg * 4;          // h-column base of this WG
    const int hcol = c0wg + (n & 3);
    const int gid  = n >> 2;          // gate group of my frag col
    const bool lowhalf = (w < 4);
    const int p    = lowhalf ? w : (w - 4);
    const int mt   = lowhalf ? 2 * p : 2 * p + 1;  // my cell tile (both layers)
    const size_t S = (size_t)Bd * Hd;

    __shared__ f16 B0[16 * 1096];       // layer0 weights [16 rows][1088+8 pad]
    __shared__ float xchg[3072];        // 12 exchange slots x 256 floats

    // ---- fill B0 (f32 -> f16): row nr -> global gate row ----
    {
        int nr = tid >> 5;              // 0..15
        int gr = (nr >> 2) * Hd + c0wg + (nr & 3);
        for (int k = tid & 31; k < 1088; k += 32) {
            float v = (k < Hd) ? Uh0[(size_t)gr * Hd + k]
                               : Wx0[(size_t)gr * INd + (k - Hd)];
            B0[nr * 1096 + k] = (f16)v;
        }
    }

    // ---- preload layer1 B frags into VGPRs (my k-half) ----
    half8 b1f[32];
    {
        const float* Wsrc = lowhalf ? Wx1 : Uh1;
        int gr = gid * Hd + c0wg + (n & 3);
        const float* rp = Wsrc + (size_t)gr * Hd + q * 8;
        #pragma unroll
        for (int kk = 0; kk < 32; ++kk) {
            half8 hv;
            #pragma unroll
            for (int j = 0; j < 8; ++j) hv[j] = (f16)rp[kk * 32 + j];
            b1f[kk] = hv;
        }
    }

    // ---- per-lane biases & c-state ----
    float gb0[4], gb1[4], bia0[4], bia1[4];
    #pragma unroll
    for (int g = 0; g < 4; ++g) {
        gb0[g] = bx0[g * Hd + hcol] + bh0[g * Hd + hcol];
        gb1[g] = bx1[g * Hd + hcol] + bh1[g * Hd + hcol];
    }
    #pragma unroll
    for (int r = 0; r < 4; ++r) {
        int row = mt * 16 + q * 4 + r;
        bia0[r] = bi0[row * Hd + hcol];
        bia1[r] = bi1[row * Hd + hcol];
    }
    f32x4 c0v = {0.f, 0.f, 0.f, 0.f};
    f32x4 c1v = {0.f, 0.f, 0.f, 0.f};

    __syncthreads();   // B0 ready

    unsigned epoch = 0;

    for (int s = -1; s <= 511; ++s) {
        const bool do_l0 = (s < 511);
        const bool do_l1 = (s >= 0);
        const int pr = s & 1;                 // s=-1 -> 1
        const f16* h0r = h0buf + (size_t)pr * S;
        f16*       h0w = h0buf + (size_t)(1 - pr) * S;
        const f16* h1r = h1buf + (size_t)(1 - pr) * S;
        f16*       h1w = h1buf + (size_t)pr * S;

        f32x4 a0a = {0.f,0.f,0.f,0.f}, a0b = {0.f,0.f,0.f,0.f};
        f32x4 a1a = {0.f,0.f,0.f,0.f}, a1b = {0.f,0.f,0.f,0.f};

        if (lowhalf) {
            const half8* pA0 = (const half8*)(h0r + (size_t)(2*p*16 + n) * Hd + q*8);
            const half8* pA1 = (const half8*)(h0r + (size_t)((2*p+1)*16 + n) * Hd + q*8);
            const half8* pB  = (const half8*)(&B0[n * 1096 + q * 8]);
            if (do_l0 && do_l1) {
                #pragma unroll
                for (int kk = 0; kk < 32; ++kk) {
                    half8 A0 = pA0[kk*4], A1 = pA1[kk*4], Bl = pB[kk*4];
                    a0a = __builtin_amdgcn_mfma_f32_16x16x32_f16(A0, Bl, a0a, 0,0,0);
                    a0b = __builtin_amdgcn_mfma_f32_16x16x32_f16(A1, Bl, a0b, 0,0,0);
                    a1a = __builtin_amdgcn_mfma_f32_16x16x32_f16(A0, b1f[kk], a1a, 0,0,0);
                    a1b = __builtin_amdgcn_mfma_f32_16x16x32_f16(A1, b1f[kk], a1b, 0,0,0);
                }
            } else if (do_l0) {          // s == -1
                #pragma unroll
                for (int kk = 0; kk < 32; ++kk) {
                    half8 A0 = pA0[kk*4], A1 = pA1[kk*4], Bl = pB[kk*4];
                    a0a = __builtin_amdgcn_mfma_f32_16x16x32_f16(A0, Bl, a0a, 0,0,0);
                    a0b = __builtin_amdgcn_mfma_f32_16x16x32_f16(A1, Bl, a0b, 0,0,0);
                }
            } else {                     // s == 511
                #pragma unroll
                for (int kk = 0; kk < 32; ++kk) {
                    half8 A0 = pA0[kk*4], A1 = pA1[kk*4];
                    a1a = __builtin_amdgcn_mfma_f32_16x16x32_f16(A0, b1f[kk], a1a, 0,0,0);
                    a1b = __builtin_amdgcn_mfma_f32_16x16x32_f16(A1, b1f[kk], a1b, 0,0,0);
                }
            }
            if (do_l0) {                 // x-projection chunks (k = 1024..1087)
                const f16* xt = xT + (size_t)(s + 1) * Bd * INd;
                const half8* pX0 = (const half8*)(xt + (size_t)(2*p*16 + n) * INd + q*8);
                const half8* pX1 = (const half8*)(xt + (size_t)((2*p+1)*16 + n) * INd + q*8);
                #pragma unroll
                for (int kk = 0; kk < 2; ++kk) {
                    half8 Bl = pB[(32 + kk) * 4];
                    a0a = __builtin_amdgcn_mfma_f32_16x16x32_f16(pX0[kk*4], Bl, a0a, 0,0,0);
                    a0b = __builtin_amdgcn_mfma_f32_16x16x32_f16(pX1[kk*4], Bl, a0b, 0,0,0);
                }
            }
        } else if (do_l1) {              // waves 4-7: layer1 k-half 1 (A = h1)
            const half8* pH1a = (const half8*)(h1r + (size_t)(2*p*16 + n) * Hd + q*8);
            const half8* pH1b = (const half8*)(h1r + (size_t)((2*p+1)*16 + n) * Hd + q*8);
            #pragma unroll
            for (int kk = 0; kk < 32; ++kk) {
                half8 A0 = pH1a[kk*4], A1 = pH1b[kk*4];
                a1a = __builtin_amdgcn_mfma_f32_16x16x32_f16(A0, b1f[kk], a1a, 0,0,0);
                a1b = __builtin_amdgcn_mfma_f32_16x16x32_f16(A1, b1f[kk], a1b, 0,0,0);
            }
        }

        // ---- exchange partials via LDS ----
        float* slotA = xchg;              // layer0 tile 2p+1 (from wave p)
        float* slotB = xchg + 1024;       // layer1 tile 2p+1 k-half0 (from wave p)
        float* slotC = xchg + 2048;       // layer1 tile 2p   k-half1 (from wave 4+p)
        if (lowhalf) {
            if (do_l0) *(f32x4*)&slotA[p * 256 + lane * 4] = a0b;
            if (do_l1) *(f32x4*)&slotB[p * 256 + lane * 4] = a1b;
        } else {
            if (do_l1) *(f32x4*)&slotC[p * 256 + lane * 4] = a1a;
        }
        __syncthreads();

        f32x4 g0acc, g1acc;
        if (lowhalf) {
            g0acc = a0a;
            if (do_l1) g1acc = a1a + *(const f32x4*)&slotC[p * 256 + lane * 4];
        } else {
            if (do_l0) g0acc = *(const f32x4*)&slotA[p * 256 + lane * 4];
            if (do_l1) g1acc = a1b + *(const f32x4*)&slotB[p * 256 + lane * 4];
        }

        // ---- cell updates (fp32), write h (f16) ----
        auto cell = [&](f32x4 acc, const float* gb, const float* bia,
                        f32x4& cst, f16* hw) {
            #pragma unroll
            for (int r = 0; r < 4; ++r) {
                float own = acc[r];
                float v4  = __shfl_xor(own, 4);
                float v8  = __shfl_xor(own, 8);
                float v12 = __shfl_xor(own, 12);
                float ip = gid==0?own: gid==1?v4 : gid==2?v8 : v12;
                float fp = gid==0?v4 : gid==1?own: gid==2?v12: v8;
                float op = gid==0?v8 : gid==1?v12: gid==2?own: v4;
                float gp = gid==0?v12: gid==1?v8 : gid==2?v4 : own;
                float I = 1.f / (1.f + expf(-(ip + gb[0])));
                float F = 1.f / (1.f + expf(-(fp + gb[1] + bia[r])));
                float O = 1.f / (1.f + expf(-(op + gb[2])));
                float G = tanhf(gp + gb[3]);
                float c = F * cst[r] + I * G;
                cst[r] = c;
                float h = O * tanhf(c);
                if (n < 4)
                    hw[(size_t)(mt * 16 + q * 4 + r) * Hd + c0wg + n] = (f16)h;
            }
        };
        if (do_l0) cell(g0acc, gb0, bia0, c0v, h0w);
        if (do_l1) cell(g1acc, gb1, bia1, c1v, h1w);

        // ---- grid barrier (monotonic counter) ----
        __syncthreads();                 // drains this WG's h-stores (vmcnt 0)
        if (tid == 0) {
            __threadfence();             // wbl2: publish to device scope
            atomicAdd(cnt, 1u);
            unsigned target = (epoch + 1) * NWG;
            while (__hip_atomic_load(cnt, __ATOMIC_RELAXED,
                                     __HIP_MEMORY_SCOPE_AGENT) < target)
                __builtin_amdgcn_s_sleep(1);
            __threadfence();             // inv: fresh L2 for next iter reads
        }
        epoch++;
        __syncthreads();
    }

    // ---- fc head: out[b] = fcW . h1(511)[b] + fcb ----
    if (blockIdx.x < Bd) {
        int b = blockIdx.x;
        const f16* hf = h1buf + S + (size_t)b * Hd;   // parity 1 holds h1(511)
        int k = tid * 2;
        float sum = (float)hf[k] * fcW[k] + (float)hf[k + 1] * fcW[k + 1];
        #pragma unroll
        for (int off = 32; off > 0; off >>= 1) sum += __shfl_down(sum, off);
        float* red = xchg;
        if (lane == 0) red[w] = sum;
        __syncthreads();
        if (tid == 0) {
            float t = 0.f;
            #pragma unroll
            for (int i = 0; i < 8; ++i) t += red[i];
            out[b] = t + fcb[0];
        }
    }
}

// ---------------------------------------------------------------------------
extern "C" void kernel_launch(void* const* d_in, const int* in_sizes, int n_in,
                              void* d_out, int out_size, void* d_ws, size_t ws_size,
                              hipStream_t stream) {
    const float* x        = (const float*)d_in[0];
    const float* boundary = (const float*)d_in[1];
    const float* Wx0      = (const float*)d_in[2];
    const float* bx0      = (const float*)d_in[3];
    const float* Uh0      = (const float*)d_in[4];
    const float* bh0      = (const float*)d_in[5];
    const float* Wb0      = (const float*)d_in[6];
    const float* bb0      = (const float*)d_in[7];
    const float* Wx1      = (const float*)d_in[8];
    const float* bx1      = (const float*)d_in[9];
    const float* Uh1      = (const float*)d_in[10];
    const float* bh1      = (const float*)d_in[11];
    const float* Wb1      = (const float*)d_in[12];
    const float* bb1      = (const float*)d_in[13];
    const float* fcW      = (const float*)d_in[14];
    const float* fcb      = (const float*)d_in[15];
    float* out = (float*)d_out;

    // workspace layout (bytes)
    char* ws = (char*)d_ws;
    f16*   xT    = (f16*)(ws);                       // 8,388,608 B
    f16*   h0buf = (f16*)(ws + 8388608);             //   524,288 B (2 parities)
    f16*   h1buf = (f16*)(ws + 8912896);             //   524,288 B
    float* bi0   = (float*)(ws + 9437184);           //   524,288 B
    float* bi1   = (float*)(ws + 9961472);           //   524,288 B
    unsigned int* cnt = (unsigned int*)(ws + 10485760);

    init_state<<<256, 512, 0, stream>>>(boundary, Wb0, bb0, Wb1, bb1,
                                        bi0, bi1, h0buf, h1buf, cnt);
    xpose<<<8192, 512, 0, stream>>>(x, xT);

    void* args[] = {
        (void*)&xT, (void*)&h0buf, (void*)&h1buf, (void*)&bi0, (void*)&bi1,
        (void*)&Wx0, (void*)&bx0, (void*)&Uh0, (void*)&bh0,
        (void*)&Wx1, (void*)&bx1, (void*)&Uh1, (void*)&bh1,
        (void*)&fcW, (void*)&fcb, (void*)&out, (void*)&cnt
    };
    hipLaunchCooperativeKernel((void*)lstm_persist, dim3(NWG), dim3(NTHR),
                               args, 0, stream);
}